// Round 9
// baseline (394.254 us; speedup 1.0000x reference)
//
#include <hip/hip_runtime.h>
#include <hip/hip_bf16.h>

#define DIM 256
#define MEMN 512
#define TEMPF 10.0f

typedef float f32x4 __attribute__((ext_vector_type(4)));
typedef __bf16 bf16x8 __attribute__((ext_vector_type(8)));
typedef unsigned int u32;
typedef unsigned short u16;

__device__ __forceinline__ u16 bf16bits(float x) {
  __bf16 h = (__bf16)x;
  return __builtin_bit_cast(u16, h);
}
__device__ __forceinline__ u32 pack2(float a, float b) {
  return (u32)bf16bits(a) | ((u32)bf16bits(b) << 16);
}

// KnFrag[kc][mt][lane][j] = Kn_norm[mt*16+(lane&15)][kc*32+(lane>>4)*8+j], kc<8, mt<32
__global__ void prep_keys(const float* __restrict__ keys, u16* __restrict__ knf) {
  int lane = threadIdx.x & 63;
  int m = blockIdx.x * 4 + (threadIdx.x >> 6);
  float4 v = *reinterpret_cast<const float4*>(keys + (size_t)m * DIM + lane * 4);
  float ss = v.x*v.x + v.y*v.y + v.z*v.z + v.w*v.w;
  #pragma unroll
  for (int o = 1; o < 64; o <<= 1) ss += __shfl_xor(ss, o);
  float rn = 1.0f / fmaxf(sqrtf(ss), 1e-12f);
  float vals[4] = {v.x*rn, v.y*rn, v.z*rn, v.w*rn};
  int mt = m >> 4, ml = m & 15;
  #pragma unroll
  for (int t = 0; t < 4; ++t) {
    int d = lane * 4 + t;
    int kc = d >> 5, gg = (d >> 3) & 3, j = d & 7;
    knf[(size_t)((kc*32 + mt)*64 + gg*16 + ml)*8 + j] = bf16bits(vals[t]);
  }
}

// VtFrag[kc][dt][lane][j] = V[kc*32+(lane>>4)*8+j][dt*16+(lane&15)], kc<16, dt<16
__global__ void prep_vals(const float* __restrict__ mv, u16* __restrict__ vtf) {
  int lane = threadIdx.x & 63;
  int m = blockIdx.x * 4 + (threadIdx.x >> 6);
  float4 v = *reinterpret_cast<const float4*>(mv + (size_t)m * DIM + lane * 4);
  float vals[4] = {v.x, v.y, v.z, v.w};
  int kc = m >> 5, gg = (m >> 3) & 3, j = m & 7;
  #pragma unroll
  for (int t = 0; t < 4; ++t) {
    int d = lane * 4 + t;
    int dt = d >> 4, dl = d & 15;
    vtf[(size_t)((kc*16 + dt)*64 + gg*16 + dl)*8 + j] = bf16bits(vals[t]);
  }
}

// LGKM-ONLY barrier: drains this wave's LDS queue then syncs. Does NOT touch
// vmcnt -> in-flight global stores keep draining in the background. Correct
// here because every cross-wave hazard is through LDS; global loads are
// register-consumed (compiler-counted waits) and stores have no reader.
#define BAR_LGKM do { \
    asm volatile("s_waitcnt lgkmcnt(0)" ::: "memory"); \
    __builtin_amdgcn_s_barrier(); \
  } while (0)

// Persistent blocks: grid 512 (2/CU), each processes 4 tiles of 64 rows.
// Per tile (round-6-verified math):
//   GEMM1: wave w owns m-quarter [128w,128w+128) x 64 rows (Q B-frags via LDS)
//   GEMM2: wave w owns d-quarter [64w,64w+64)   x 64 rows (W B-frags via LDS)
// A-fragments (K,V) direct from global (L2-resident). No vmcnt waits anywhere
// in the loop -> output stores overlap the next tile's compute.
__global__ __launch_bounds__(256, 2) void fused_main(
    const float* __restrict__ q, const u16* __restrict__ knf,
    const u16* __restrict__ vtf, float* __restrict__ out_o,
    float* __restrict__ out_w, float* __restrict__ out_s, int ntiles) {
  // [0,32768): Q-frags (gr*8+kc)*1024 + lane*16 (dead after GEMM1)
  // [0,65536): W-frags (kcw*4+gr)*1024 + lane*16 (overlays Q after barrier #2)
  // [65536,66560): psb row-sum partials; [66560,66816): rnb 1/||q||
  __shared__ __align__(16) char lds[66816];
  const int tid = threadIdx.x;
  const int wave = tid >> 6, lane = tid & 63;
  const int g = lane >> 4, c = lane & 15;

  float* psb = reinterpret_cast<float*>(lds + 65536);
  float* rnb = reinterpret_cast<float*>(lds + 66560);

  for (int tile = blockIdx.x; tile < ntiles; tile += gridDim.x) {
    const int browbase = tile * 64;
    const int myrow = browbase + wave * 16 + c;

    // #0 (loop-top): all waves done with previous tile's LDS reads before the
    // new Q-frag writes overlay the region. lgkm-only: prev stores keep flying.
    BAR_LGKM;

    // ---- prologue: own 16 rows' Q -> scene diff, sum-sq, bf16 B-frags to LDS
    const float* qrow = q + (size_t)myrow * DIM + g * 8;
    float sd = 0.f, ss = 0.f;
    #pragma unroll
    for (int kc = 0; kc < 8; ++kc) {
      float4 a = *reinterpret_cast<const float4*>(qrow + kc * 32);
      float4 b = *reinterpret_cast<const float4*>(qrow + kc * 32 + 4);
      float x[8] = {a.x, a.y, a.z, a.w, b.x, b.y, b.z, b.w};
      bf16x8 qb;
      #pragma unroll
      for (int e = 0; e < 8; ++e) {
        float nb = __shfl_down(x[e], 1);       // row c+1 (valid c<15)
        float d0 = nb - x[e];
        sd += d0 * d0;
        ss += x[e] * x[e];
        qb[e] = (__bf16)x[e];                  // deferred norm -> exp scale
      }
      *reinterpret_cast<bf16x8*>(lds + (wave*8 + kc)*1024 + lane*16) = qb;
    }
    sd += __shfl_xor(sd, 16); sd += __shfl_xor(sd, 32);
    ss += __shfl_xor(ss, 16); ss += __shfl_xor(ss, 32);
    if (g == 0 && c < 15)
      out_s[myrow] = (sqrtf(sd) < 0.8f) ? 1.0f : 0.0f;
    float rn = 1.0f / fmaxf(sqrtf(ss), 1e-12f);
    if (g == 0) rnb[wave*16 + c] = rn;
    BAR_LGKM;                                  // #1: Q-frags + rn visible

    float scale_r[4];
    #pragma unroll
    for (int gr = 0; gr < 4; ++gr) scale_r[gr] = TEMPF * rnb[gr*16 + c];

    // ---- GEMM1: S^T[m in wave-quarter][64 rows]; A (K) direct from L2
    f32x4 acc[8][4];
    #pragma unroll
    for (int mt = 0; mt < 8; ++mt)
      #pragma unroll
      for (int gr = 0; gr < 4; ++gr) { f32x4 z = {}; acc[mt][gr] = z; }

    #pragma unroll
    for (int kc = 0; kc < 8; ++kc) {
      bf16x8 bfr[4];
      #pragma unroll
      for (int gr = 0; gr < 4; ++gr)
        bfr[gr] = *reinterpret_cast<const bf16x8*>(lds + (gr*8 + kc)*1024 + lane*16);
      bf16x8 afr[8];
      #pragma unroll
      for (int mt = 0; mt < 8; ++mt)
        afr[mt] = *reinterpret_cast<const bf16x8*>(
            knf + (size_t)(kc*32 + wave*8 + mt)*512 + lane*8);
      #pragma unroll
      for (int mt = 0; mt < 8; ++mt)
        #pragma unroll
        for (int gr = 0; gr < 4; ++gr)
          acc[mt][gr] = __builtin_amdgcn_mfma_f32_16x16x32_bf16(afr[mt], bfr[gr], acc[mt][gr], 0, 0, 0);
    }
    // acc[mt][gr][i] = S^T[m=128w+16mt+4g+i][row=gr*16+c]

    // ---- exp + partial row sums
    float psum[4] = {0.f, 0.f, 0.f, 0.f};
    #pragma unroll
    for (int mt = 0; mt < 8; ++mt)
      #pragma unroll
      for (int gr = 0; gr < 4; ++gr)
        #pragma unroll
        for (int i = 0; i < 4; ++i) {
          float e = __expf(acc[mt][gr][i] * scale_r[gr]);
          acc[mt][gr][i] = e;
          psum[gr] += e;
        }
    #pragma unroll
    for (int gr = 0; gr < 4; ++gr) {
      psum[gr] += __shfl_xor(psum[gr], 16);
      psum[gr] += __shfl_xor(psum[gr], 32);
    }
    if (g == 0) {
      #pragma unroll
      for (int gr = 0; gr < 4; ++gr)
        psb[(wave*4 + gr)*16 + c] = psum[gr];
    }
    BAR_LGKM;                                  // #2: partials visible; Q reads done

    float rcp_r[4];
    #pragma unroll
    for (int gr = 0; gr < 4; ++gr) {
      float t = psb[(0*4 + gr)*16 + c] + psb[(1*4 + gr)*16 + c]
              + psb[(2*4 + gr)*16 + c] + psb[(3*4 + gr)*16 + c];
      rcp_r[gr] = 1.0f / t;
    }

    // ---- W-frags (bf16, rcp-folded) into LDS (overlays Q region)
    // slot (kcw,gr): lane (g2,c2) j holds W[gr*16+c2][kcw*32+g2*8+j]
    // writer: kcw=4w+(mt>>1), g2=(mt&1)*2+(g>>1), j0=(g&1)*4 (round-6-verified)
    #pragma unroll
    for (int mt = 0; mt < 8; ++mt) {
      int kcw = 4*wave + (mt >> 1);
      int lane_t = ((mt & 1)*2 + (g >> 1))*16 + c;
      #pragma unroll
      for (int gr = 0; gr < 4; ++gr) {
        u32 lo = pack2(acc[mt][gr][0]*rcp_r[gr], acc[mt][gr][1]*rcp_r[gr]);
        u32 hi = pack2(acc[mt][gr][2]*rcp_r[gr], acc[mt][gr][3]*rcp_r[gr]);
        u32* dst = reinterpret_cast<u32*>(lds + (size_t)(kcw*4 + gr)*1024 + lane_t*16 + (g & 1)*8);
        dst[0] = lo; dst[1] = hi;
      }
    }
    // W f32 global, groups 0,1 (drain under GEMM2; no waits)
    #pragma unroll
    for (int mt = 0; mt < 8; ++mt)
      #pragma unroll
      for (int gr = 0; gr < 2; ++gr) {
        float4 wv = { acc[mt][gr][0]*rcp_r[gr], acc[mt][gr][1]*rcp_r[gr],
                      acc[mt][gr][2]*rcp_r[gr], acc[mt][gr][3]*rcp_r[gr] };
        *reinterpret_cast<float4*>(out_w + (size_t)(browbase + gr*16 + c)*MEMN
                                   + (wave*8 + mt)*16 + 4*g) = wv;
      }
    BAR_LGKM;                                  // #3: W-frags visible

    // ---- GEMM2: O^T[d in wave-quarter][64 rows]; A (V) direct from L2
    f32x4 oacc[4][4];
    #pragma unroll
    for (int dt = 0; dt < 4; ++dt)
      #pragma unroll
      for (int gr = 0; gr < 4; ++gr) { f32x4 z = {}; oacc[dt][gr] = z; }

    #pragma unroll
    for (int kc2 = 0; kc2 < 16; ++kc2) {
      bf16x8 bfr[4];
      #pragma unroll
      for (int gr = 0; gr < 4; ++gr)
        bfr[gr] = *reinterpret_cast<const bf16x8*>(lds + (size_t)(kc2*4 + gr)*1024 + lane*16);
      bf16x8 afr[4];
      #pragma unroll
      for (int dt = 0; dt < 4; ++dt)
        afr[dt] = *reinterpret_cast<const bf16x8*>(
            vtf + (size_t)(kc2*16 + wave*4 + dt)*512 + lane*8);
      {   // spread W store: kc2 -> (mt=kc2>>1, gr=2+(kc2&1))
        int mt = kc2 >> 1, gr2 = 2 + (kc2 & 1);
        float4 wv = { acc[mt][gr2][0]*rcp_r[gr2], acc[mt][gr2][1]*rcp_r[gr2],
                      acc[mt][gr2][2]*rcp_r[gr2], acc[mt][gr2][3]*rcp_r[gr2] };
        *reinterpret_cast<float4*>(out_w + (size_t)(browbase + gr2*16 + c)*MEMN
                                   + (wave*8 + mt)*16 + 4*g) = wv;
      }
      #pragma unroll
      for (int dt = 0; dt < 4; ++dt)
        #pragma unroll
        for (int gr = 0; gr < 4; ++gr)
          oacc[dt][gr] = __builtin_amdgcn_mfma_f32_16x16x32_bf16(afr[dt], bfr[gr], oacc[dt][gr], 0, 0, 0);
    }

    // ---- O store (drains under next tile's prologue/GEMM1)
    #pragma unroll
    for (int dt = 0; dt < 4; ++dt)
      #pragma unroll
      for (int gr = 0; gr < 4; ++gr) {
        float4 ov = { oacc[dt][gr][0], oacc[dt][gr][1], oacc[dt][gr][2], oacc[dt][gr][3] };
        *reinterpret_cast<float4*>(out_o + (size_t)(browbase + gr*16 + c)*DIM
                                   + (wave*4 + dt)*16 + 4*g) = ov;
      }
  }
}

// Boundary scene diffs: i % 16 == 15 (one wave per i)
__global__ void scene_bound(const float* __restrict__ q, float* __restrict__ out_s, int B) {
  int widx = (blockIdx.x * blockDim.x + threadIdx.x) >> 6;
  int lane = threadIdx.x & 63;
  int i = widx * 16 + 15;
  if (i > B - 2) return;
  const float* a = q + (size_t)i * DIM + lane * 4;
  float4 x = *reinterpret_cast<const float4*>(a);
  float4 y = *reinterpret_cast<const float4*>(a + DIM);
  float dx = y.x-x.x, dy = y.y-x.y, dz = y.z-x.z, dw = y.w-x.w;
  float sd = dx*dx + dy*dy + dz*dz + dw*dw;
  #pragma unroll
  for (int o = 1; o < 64; o <<= 1) sd += __shfl_xor(sd, o);
  if (lane == 0) out_s[i] = (sqrtf(sd) < 0.8f) ? 1.0f : 0.0f;
}

extern "C" void kernel_launch(void* const* d_in, const int* in_sizes, int n_in,
                              void* d_out, int out_size, void* d_ws, size_t ws_size,
                              hipStream_t stream) {
  const float* q  = (const float*)d_in[0];
  const float* mk = (const float*)d_in[1];
  const float* mv = (const float*)d_in[2];
  int B = in_sizes[0] / DIM;            // 131072
  float* o = (float*)d_out;
  float* w = o + (size_t)B * DIM;
  float* s = w + (size_t)B * MEMN;
  u16* knf = (u16*)d_ws;                         // 256 KB
  u16* vtf = (u16*)((char*)d_ws + 262144);       // 256 KB
  prep_keys<<<128, 256, 0, stream>>>(mk, knf);
  prep_vals<<<128, 256, 0, stream>>>(mv, vtf);
  int ntiles = B / 64;                           // 2048
  fused_main<<<512, 256, 0, stream>>>(q, knf, vtf, o, w, s, ntiles);
  int nwaves = B / 16;
  scene_bound<<<(nwaves + 3) / 4, 256, 0, stream>>>(q, s, B);
}

// Round 11
// 246.066 us; speedup vs baseline: 1.6022x; 1.6022x over previous
//
#include <hip/hip_runtime.h>
#include <hip/hip_bf16.h>

#define DIM 256
#define MEMN 512
#define TEMPF 10.0f

typedef float f32x4 __attribute__((ext_vector_type(4)));
typedef __bf16 bf16x8 __attribute__((ext_vector_type(8)));
typedef unsigned int u32;
typedef unsigned short u16;
typedef u32 u32x4 __attribute__((ext_vector_type(4)));

__device__ __forceinline__ u16 bf16bits(float x) {
  __bf16 h = (__bf16)x;
  return __builtin_bit_cast(u16, h);
}
__device__ __forceinline__ u32 pack2(float a, float b) {
  return (u32)bf16bits(a) | ((u32)bf16bits(b) << 16);
}

// KnFrag[kc][mt][lane][j] = Kn_norm[mt*16+(lane&15)][kc*32+(lane>>4)*8+j], kc<8, mt<32
__global__ void prep_keys(const float* __restrict__ keys, u16* __restrict__ knf) {
  int lane = threadIdx.x & 63;
  int m = blockIdx.x * 4 + (threadIdx.x >> 6);
  float4 v = *reinterpret_cast<const float4*>(keys + (size_t)m * DIM + lane * 4);
  float ss = v.x*v.x + v.y*v.y + v.z*v.z + v.w*v.w;
  #pragma unroll
  for (int o = 1; o < 64; o <<= 1) ss += __shfl_xor(ss, o);
  float rn = 1.0f / fmaxf(sqrtf(ss), 1e-12f);
  float vals[4] = {v.x*rn, v.y*rn, v.z*rn, v.w*rn};
  int mt = m >> 4, ml = m & 15;
  #pragma unroll
  for (int t = 0; t < 4; ++t) {
    int d = lane * 4 + t;
    int kc = d >> 5, gg = (d >> 3) & 3, j = d & 7;
    knf[(size_t)((kc*32 + mt)*64 + gg*16 + ml)*8 + j] = bf16bits(vals[t]);
  }
}

// VtFrag[kc][dt][lane][j] = V[kc*32+(lane>>4)*8+j][dt*16+(lane&15)], kc<16, dt<16
__global__ void prep_vals(const float* __restrict__ mv, u16* __restrict__ vtf) {
  int lane = threadIdx.x & 63;
  int m = blockIdx.x * 4 + (threadIdx.x >> 6);
  float4 v = *reinterpret_cast<const float4*>(mv + (size_t)m * DIM + lane * 4);
  float vals[4] = {v.x, v.y, v.z, v.w};
  int kc = m >> 5, gg = (m >> 3) & 3, j = m & 7;
  #pragma unroll
  for (int t = 0; t < 4; ++t) {
    int d = lane * 4 + t;
    int dt = d >> 4, dl = d & 15;
    vtf[(size_t)((kc*16 + dt)*64 + gg*16 + dl)*8 + j] = bf16bits(vals[t]);
  }
}

// Fully wave-independent kernel: 4 waves/block, each wave owns 16 rows
// end-to-end. NO LDS storage, NO barriers, NO manual waitcnt. A-fragments
// (K,V) read directly from global (L2-resident, kept hot by NT streaming of
// Q/W/O). Per-wave math identical to the round-1..5 verified chain:
//   GEMM1: S^T = mfma(A=KnFrag, B=Qbf) -> row c's 512 logits lane-local
//          across g (acc[mt][i] = S^T[m=16mt+4g+i][row c])
//   softmax: 128 local exps + shfl_xor(16,32); deferred ||q|| in exp scale
//   W-exchange: bf16 pairs via 8 ds_bpermute per kc2 (addrA/addrB/hig)
//   GEMM2: O^T = mfma(A=VtFrag, B=Wbf), O scaled by lane-local rcp
__global__ __launch_bounds__(256, 2) void fused_main(
    const float* __restrict__ q, const u16* __restrict__ knf,
    const u16* __restrict__ vtf, float* __restrict__ out_o,
    float* __restrict__ out_w, float* __restrict__ out_s) {
  const int lane = threadIdx.x & 63;
  const int wave = threadIdx.x >> 6;
  const int g = lane >> 4, c = lane & 15;
  const int row = blockIdx.x * 64 + wave * 16 + c;

  // ---- Q load (nontemporal: read-once, don't pollute L2), scene, sum-sq
  const float* qrow = q + (size_t)row * DIM + g * 8;
  float sd = 0.f, ss = 0.f;
  bf16x8 qbf[8];
  #pragma unroll
  for (int kc = 0; kc < 8; ++kc) {
    f32x4 a = __builtin_nontemporal_load(reinterpret_cast<const f32x4*>(qrow + kc*32));
    f32x4 b = __builtin_nontemporal_load(reinterpret_cast<const f32x4*>(qrow + kc*32 + 4));
    float x[8] = {a[0], a[1], a[2], a[3], b[0], b[1], b[2], b[3]};
    #pragma unroll
    for (int e = 0; e < 8; ++e) {
      float nb = __shfl_down(x[e], 1);     // row c+1 (valid c<15; c==15 -> scene_bound)
      float d0 = nb - x[e];
      sd += d0 * d0;
      ss += x[e] * x[e];
      qbf[kc][e] = (__bf16)x[e];           // deferred norm -> folded into exp scale
    }
  }
  sd += __shfl_xor(sd, 16); sd += __shfl_xor(sd, 32);
  ss += __shfl_xor(ss, 16); ss += __shfl_xor(ss, 32);
  if (g == 0 && c < 15)
    out_s[row] = (sqrtf(sd) < 0.8f) ? 1.0f : 0.0f;
  float scale = TEMPF / fmaxf(sqrtf(ss), 1e-12f);

  // ---- GEMM1: S^T[512 x 16]; A (K) direct from global/L2
  f32x4 acc[32];
  #pragma unroll
  for (int mt = 0; mt < 32; ++mt) { f32x4 z = {}; acc[mt] = z; }

  #pragma unroll
  for (int kc = 0; kc < 8; ++kc) {
    #pragma unroll
    for (int mb = 0; mb < 4; ++mb) {       // 8-load batches -> ILP + bounded regs
      bf16x8 afr[8];
      #pragma unroll
      for (int t = 0; t < 8; ++t)
        afr[t] = *reinterpret_cast<const bf16x8*>(
            knf + (size_t)(kc*32 + mb*8 + t)*512 + lane*8);
      #pragma unroll
      for (int t = 0; t < 8; ++t)
        acc[mb*8+t] = __builtin_amdgcn_mfma_f32_16x16x32_bf16(afr[t], qbf[kc], acc[mb*8+t], 0, 0, 0);
    }
  }

  // ---- softmax (|logit*scale| <= 10, fp32-safe without max-sub)
  float sum = 0.f;
  #pragma unroll
  for (int mt = 0; mt < 32; ++mt) {
    #pragma unroll
    for (int i = 0; i < 4; ++i) {
      float e = __expf(acc[mt][i] * scale);
      acc[mt][i] = e;
      sum += e;
    }
  }
  sum += __shfl_xor(sum, 16); sum += __shfl_xor(sum, 32);
  float rcp = 1.0f / sum;

  // ---- W store (nontemporal, rcp-folded) + bf16 pair pack for GEMM2
  u32 hpair[64];                            // hpair[mt*2+s] = bf16x2(e[2s],e[2s+1]) of tile mt
  float* wrow = out_w + (size_t)row * MEMN + g * 4;
  #pragma unroll
  for (int mt = 0; mt < 32; ++mt) {
    f32x4 wv = { acc[mt][0]*rcp, acc[mt][1]*rcp, acc[mt][2]*rcp, acc[mt][3]*rcp };
    __builtin_nontemporal_store(wv, reinterpret_cast<f32x4*>(wrow + mt * 16));
    hpair[mt*2+0] = pack2(acc[mt][0], acc[mt][1]);
    hpair[mt*2+1] = pack2(acc[mt][2], acc[mt][3]);
  }

  // ---- GEMM2: O^T[256 x 16]; A (V) direct from global/L2, B via bpermute
  f32x4 oacc[16];
  #pragma unroll
  for (int dt = 0; dt < 16; ++dt) { f32x4 z = {}; oacc[dt] = z; }

  const int addrA = ((2*(g&1) + 0)*16 + c) * 4;
  const int addrB = ((2*(g&1) + 1)*16 + c) * 4;
  const bool hig = (g >= 2);

  #pragma unroll
  for (int kc2 = 0; kc2 < 16; ++kc2) {
    u32x4 wf;
    {
      int v1 = __builtin_amdgcn_ds_bpermute(addrA, (int)hpair[4*kc2+0]);
      int v2 = __builtin_amdgcn_ds_bpermute(addrA, (int)hpair[4*kc2+2]);
      wf[0] = (u32)(hig ? v2 : v1);
      v1 = __builtin_amdgcn_ds_bpermute(addrA, (int)hpair[4*kc2+1]);
      v2 = __builtin_amdgcn_ds_bpermute(addrA, (int)hpair[4*kc2+3]);
      wf[1] = (u32)(hig ? v2 : v1);
      v1 = __builtin_amdgcn_ds_bpermute(addrB, (int)hpair[4*kc2+0]);
      v2 = __builtin_amdgcn_ds_bpermute(addrB, (int)hpair[4*kc2+2]);
      wf[2] = (u32)(hig ? v2 : v1);
      v1 = __builtin_amdgcn_ds_bpermute(addrB, (int)hpair[4*kc2+1]);
      v2 = __builtin_amdgcn_ds_bpermute(addrB, (int)hpair[4*kc2+3]);
      wf[3] = (u32)(hig ? v2 : v1);
    }
    bf16x8 bfrag = __builtin_bit_cast(bf16x8, wf);
    #pragma unroll
    for (int db = 0; db < 2; ++db) {
      bf16x8 afr[8];
      #pragma unroll
      for (int t = 0; t < 8; ++t)
        afr[t] = *reinterpret_cast<const bf16x8*>(
            vtf + (size_t)(kc2*16 + db*8 + t)*512 + lane*8);
      #pragma unroll
      for (int t = 0; t < 8; ++t)
        oacc[db*8+t] = __builtin_amdgcn_mfma_f32_16x16x32_bf16(afr[t], bfrag, oacc[db*8+t], 0, 0, 0);
    }
  }

  // ---- O store (nontemporal, scaled by lane-local rcp for row c)
  float* orow = out_o + (size_t)row * DIM + g * 4;
  #pragma unroll
  for (int dt = 0; dt < 16; ++dt) {
    f32x4 ov = { oacc[dt][0]*rcp, oacc[dt][1]*rcp, oacc[dt][2]*rcp, oacc[dt][3]*rcp };
    __builtin_nontemporal_store(ov, reinterpret_cast<f32x4*>(orow + dt * 16));
  }
}

// Boundary scene diffs: i % 16 == 15 (one wave per i)
__global__ void scene_bound(const float* __restrict__ q, float* __restrict__ out_s, int B) {
  int widx = (blockIdx.x * blockDim.x + threadIdx.x) >> 6;
  int lane = threadIdx.x & 63;
  int i = widx * 16 + 15;
  if (i > B - 2) return;
  const float* a = q + (size_t)i * DIM + lane * 4;
  float4 x = *reinterpret_cast<const float4*>(a);
  float4 y = *reinterpret_cast<const float4*>(a + DIM);
  float dx = y.x-x.x, dy = y.y-x.y, dz = y.z-x.z, dw = y.w-x.w;
  float sd = dx*dx + dy*dy + dz*dz + dw*dw;
  #pragma unroll
  for (int o = 1; o < 64; o <<= 1) sd += __shfl_xor(sd, o);
  if (lane == 0) out_s[i] = (sqrtf(sd) < 0.8f) ? 1.0f : 0.0f;
}

extern "C" void kernel_launch(void* const* d_in, const int* in_sizes, int n_in,
                              void* d_out, int out_size, void* d_ws, size_t ws_size,
                              hipStream_t stream) {
  const float* q  = (const float*)d_in[0];
  const float* mk = (const float*)d_in[1];
  const float* mv = (const float*)d_in[2];
  int B = in_sizes[0] / DIM;            // 131072
  float* o = (float*)d_out;
  float* w = o + (size_t)B * DIM;
  float* s = w + (size_t)B * MEMN;
  u16* knf = (u16*)d_ws;                         // 256 KB
  u16* vtf = (u16*)((char*)d_ws + 262144);       // 256 KB
  prep_keys<<<128, 256, 0, stream>>>(mk, knf);
  prep_vals<<<128, 256, 0, stream>>>(mv, vtf);
  fused_main<<<B / 64, 256, 0, stream>>>(q, knf, vtf, o, w, s);
  int nwaves = B / 16;
  scene_bound<<<(nwaves + 3) / 4, 256, 0, stream>>>(q, s, B);
}

// Round 12
// 153.829 us; speedup vs baseline: 2.5629x; 1.5996x over previous
//
#include <hip/hip_runtime.h>
#include <hip/hip_bf16.h>

#define DIM 256
#define MEMN 512
#define TEMPF 10.0f

typedef float f32x4 __attribute__((ext_vector_type(4)));
typedef __bf16 bf16x8 __attribute__((ext_vector_type(8)));
typedef unsigned int u32;
typedef unsigned short u16;

__device__ __forceinline__ u16 bf16bits(float x) {
  __bf16 h = (__bf16)x;
  return __builtin_bit_cast(u16, h);
}
__device__ __forceinline__ u32 pack2(float a, float b) {
  return (u32)bf16bits(a) | ((u32)bf16bits(b) << 16);
}

// KnFrag[kc][mt][lane][j] = Kn_norm[mt*16+(lane&15)][kc*32+(lane>>4)*8+j], kc<8, mt<32
__global__ void prep_keys(const float* __restrict__ keys, u16* __restrict__ knf) {
  int lane = threadIdx.x & 63;
  int m = blockIdx.x * 4 + (threadIdx.x >> 6);
  float4 v = *reinterpret_cast<const float4*>(keys + (size_t)m * DIM + lane * 4);
  float ss = v.x*v.x + v.y*v.y + v.z*v.z + v.w*v.w;
  #pragma unroll
  for (int o = 1; o < 64; o <<= 1) ss += __shfl_xor(ss, o);
  float rn = 1.0f / fmaxf(sqrtf(ss), 1e-12f);
  float vals[4] = {v.x*rn, v.y*rn, v.z*rn, v.w*rn};
  int mt = m >> 4, ml = m & 15;
  #pragma unroll
  for (int t = 0; t < 4; ++t) {
    int d = lane * 4 + t;
    int kc = d >> 5, gg = (d >> 3) & 3, j = d & 7;
    knf[(size_t)((kc*32 + mt)*64 + gg*16 + ml)*8 + j] = bf16bits(vals[t]);
  }
}

// VtFrag[kc][dt][lane][j] = V[kc*32+(lane>>4)*8+j][dt*16+(lane&15)], kc<16, dt<16
__global__ void prep_vals(const float* __restrict__ mv, u16* __restrict__ vtf) {
  int lane = threadIdx.x & 63;
  int m = blockIdx.x * 4 + (threadIdx.x >> 6);
  float4 v = *reinterpret_cast<const float4*>(mv + (size_t)m * DIM + lane * 4);
  float vals[4] = {v.x, v.y, v.z, v.w};
  int kc = m >> 5, gg = (m >> 3) & 3, j = m & 7;
  #pragma unroll
  for (int t = 0; t < 4; ++t) {
    int d = lane * 4 + t;
    int dt = d >> 4, dl = d & 15;
    vtf[(size_t)((kc*16 + dt)*64 + gg*16 + dl)*8 + j] = bf16bits(vals[t]);
  }
}

// lgkm-only barrier (round-9-validated): drains this wave's LDS queue, syncs
// waves, never touches vmcnt -> global stores drain in the background.
#define BAR_LGKM do { \
    asm volatile("s_waitcnt lgkmcnt(0)" ::: "memory"); \
    __builtin_amdgcn_s_barrier(); \
  } while (0)

// 256 threads (4 waves), 64 rows/block, 2 blocks/CU. Round-6-verified math:
//   GEMM1: wave w owns m-quarter [128w,128w+128) x 64 rows (Q B-frags via LDS)
//   GEMM2: wave w owns d-quarter [64w,64w+64)   x 64 rows (W B-frags via LDS)
// A-frags (K,V) direct from L2. Q loads NT (L3-served, no L2 pollution).
// Outputs: transposed in WAVE-PRIVATE LDS (frag region, dead after GEMM2) and
// stored nontemporal as full-line segments (O: 256B, W: 512B) -> no partial-
// line amplification, no L2 write-allocate thrash, no vmcnt drains anywhere.
__global__ __launch_bounds__(256, 2) void fused_main(
    const float* __restrict__ q, const u16* __restrict__ knf,
    const u16* __restrict__ vtf, float* __restrict__ out_o,
    float* __restrict__ out_w, float* __restrict__ out_s) {
  // [0,32768): Q-frags (gr*8+kc)*1024 + lane*16 (dead after GEMM1)
  // [0,65536): W-frags (kcw*4+gr)*1024 + lane*16 (overlay, dead after GEMM2)
  //            then wave-private epilogue regions [wave*16KB, +16KB)
  // [65536,66560): psb row-sum partials; [66560,66816): rnb 1/||q||
  __shared__ __align__(16) char lds[66816];
  const int tid = threadIdx.x;
  const int wave = tid >> 6, lane = tid & 63;
  const int g = lane >> 4, c = lane & 15;
  const int browbase = blockIdx.x * 64;
  const int myrow = browbase + wave * 16 + c;

  float* psb = reinterpret_cast<float*>(lds + 65536);
  float* rnb = reinterpret_cast<float*>(lds + 66560);

  // ---- prologue: own 16 rows' Q (NT loads) -> scene, sum-sq, bf16 frags
  const float* qrow = q + (size_t)myrow * DIM + g * 8;
  float sd = 0.f, ss = 0.f;
  #pragma unroll
  for (int kc = 0; kc < 8; ++kc) {
    f32x4 a = __builtin_nontemporal_load(reinterpret_cast<const f32x4*>(qrow + kc*32));
    f32x4 b = __builtin_nontemporal_load(reinterpret_cast<const f32x4*>(qrow + kc*32 + 4));
    float x[8] = {a[0], a[1], a[2], a[3], b[0], b[1], b[2], b[3]};
    bf16x8 qb;
    #pragma unroll
    for (int e = 0; e < 8; ++e) {
      float nb = __shfl_down(x[e], 1);       // row c+1 (valid c<15)
      float d0 = nb - x[e];
      sd += d0 * d0;
      ss += x[e] * x[e];
      qb[e] = (__bf16)x[e];                  // deferred norm -> exp scale
    }
    *reinterpret_cast<bf16x8*>(lds + (wave*8 + kc)*1024 + lane*16) = qb;
  }
  sd += __shfl_xor(sd, 16); sd += __shfl_xor(sd, 32);
  ss += __shfl_xor(ss, 16); ss += __shfl_xor(ss, 32);
  if (g == 0 && c < 15)
    out_s[myrow] = (sqrtf(sd) < 0.8f) ? 1.0f : 0.0f;
  float rn = 1.0f / fmaxf(sqrtf(ss), 1e-12f);
  if (g == 0) rnb[wave*16 + c] = rn;
  BAR_LGKM;                                  // #1: Q-frags + rn visible

  float scale_r[4];
  #pragma unroll
  for (int gr = 0; gr < 4; ++gr) scale_r[gr] = TEMPF * rnb[gr*16 + c];

  // ---- GEMM1: S^T[m in wave-quarter][64 rows]; A (K) direct from L2
  f32x4 acc[8][4];
  #pragma unroll
  for (int mt = 0; mt < 8; ++mt)
    #pragma unroll
    for (int gr = 0; gr < 4; ++gr) { f32x4 z = {}; acc[mt][gr] = z; }

  #pragma unroll
  for (int kc = 0; kc < 8; ++kc) {
    bf16x8 bfr[4];
    #pragma unroll
    for (int gr = 0; gr < 4; ++gr)
      bfr[gr] = *reinterpret_cast<const bf16x8*>(lds + (gr*8 + kc)*1024 + lane*16);
    bf16x8 afr[8];
    #pragma unroll
    for (int mt = 0; mt < 8; ++mt)
      afr[mt] = *reinterpret_cast<const bf16x8*>(
          knf + (size_t)(kc*32 + wave*8 + mt)*512 + lane*8);
    #pragma unroll
    for (int mt = 0; mt < 8; ++mt)
      #pragma unroll
      for (int gr = 0; gr < 4; ++gr)
        acc[mt][gr] = __builtin_amdgcn_mfma_f32_16x16x32_bf16(afr[mt], bfr[gr], acc[mt][gr], 0, 0, 0);
  }
  // acc[mt][gr][i] = S^T[m=128w+16mt+4g+i][row=gr*16+c]

  // ---- exp + partial row sums
  float psum[4] = {0.f, 0.f, 0.f, 0.f};
  #pragma unroll
  for (int mt = 0; mt < 8; ++mt)
    #pragma unroll
    for (int gr = 0; gr < 4; ++gr)
      #pragma unroll
      for (int i = 0; i < 4; ++i) {
        float e = __expf(acc[mt][gr][i] * scale_r[gr]);
        acc[mt][gr][i] = e;
        psum[gr] += e;
      }
  #pragma unroll
  for (int gr = 0; gr < 4; ++gr) {
    psum[gr] += __shfl_xor(psum[gr], 16);
    psum[gr] += __shfl_xor(psum[gr], 32);
  }
  if (g == 0) {
    #pragma unroll
    for (int gr = 0; gr < 4; ++gr)
      psb[(wave*4 + gr)*16 + c] = psum[gr];
  }
  BAR_LGKM;                                  // #2: partials visible; Q reads done

  float rcp_r[4];
  #pragma unroll
  for (int gr = 0; gr < 4; ++gr) {
    float t = psb[(0*4 + gr)*16 + c] + psb[(1*4 + gr)*16 + c]
            + psb[(2*4 + gr)*16 + c] + psb[(3*4 + gr)*16 + c];
    rcp_r[gr] = 1.0f / t;
  }
  // fold rcp: acc becomes final W (f32)
  #pragma unroll
  for (int mt = 0; mt < 8; ++mt)
    #pragma unroll
    for (int gr = 0; gr < 4; ++gr)
      #pragma unroll
      for (int i = 0; i < 4; ++i)
        acc[mt][gr][i] *= rcp_r[gr];

  // ---- W-frags (bf16) into LDS (overlays Q region); round-6-verified mapping
  #pragma unroll
  for (int mt = 0; mt < 8; ++mt) {
    int kcw = 4*wave + (mt >> 1);
    int lane_t = ((mt & 1)*2 + (g >> 1))*16 + c;
    #pragma unroll
    for (int gr = 0; gr < 4; ++gr) {
      u32 lo = pack2(acc[mt][gr][0], acc[mt][gr][1]);
      u32 hi = pack2(acc[mt][gr][2], acc[mt][gr][3]);
      u32* dst = reinterpret_cast<u32*>(lds + (size_t)(kcw*4 + gr)*1024 + lane_t*16 + (g & 1)*8);
      dst[0] = lo; dst[1] = hi;
    }
  }
  BAR_LGKM;                                  // #3: W-frags visible

  // ---- GEMM2: O^T[d in wave-quarter][64 rows]; A (V) direct from L2
  f32x4 oacc[4][4];
  #pragma unroll
  for (int dt = 0; dt < 4; ++dt)
    #pragma unroll
    for (int gr = 0; gr < 4; ++gr) { f32x4 z = {}; oacc[dt][gr] = z; }

  #pragma unroll
  for (int kc2 = 0; kc2 < 16; ++kc2) {
    bf16x8 bfr[4];
    #pragma unroll
    for (int gr = 0; gr < 4; ++gr)
      bfr[gr] = *reinterpret_cast<const bf16x8*>(lds + (size_t)(kc2*4 + gr)*1024 + lane*16);
    bf16x8 afr[4];
    #pragma unroll
    for (int dt = 0; dt < 4; ++dt)
      afr[dt] = *reinterpret_cast<const bf16x8*>(
          vtf + (size_t)(kc2*16 + wave*4 + dt)*512 + lane*8);
    #pragma unroll
    for (int dt = 0; dt < 4; ++dt)
      #pragma unroll
      for (int gr = 0; gr < 4; ++gr)
        oacc[dt][gr] = __builtin_amdgcn_mfma_f32_16x16x32_bf16(afr[dt], bfr[gr], oacc[dt][gr], 0, 0, 0);
  }
  BAR_LGKM;                                  // #4: frag region dead -> private use

  // ---- epilogue (wave-private 16KB region; only compiler lgkm waits needed)
  char* priv = lds + wave * 16384;

  // O: oacc[dt][gr][i] = O[row=gr*16+c][d=64w+dt*16+4g+i]. Transpose in priv
  // (64 rows x 256B, XOR-swizzle key (row&15)<<4), then NT-store 256B/row.
  #pragma unroll
  for (int dt = 0; dt < 4; ++dt)
    #pragma unroll
    for (int gr = 0; gr < 4; ++gr) {
      int row = gr*16 + c;
      *reinterpret_cast<f32x4*>(priv + row*256 + ((dt*64 + g*16) ^ (c << 4))) = oacc[dt][gr];
    }
  #pragma unroll
  for (int p = 0; p < 16; ++p) {
    int rq = lane >> 4, cc = lane & 15;
    int rowp = 4*p + rq;
    f32x4 t = *reinterpret_cast<const f32x4*>(priv + rowp*256 + ((cc*16) ^ ((rowp & 15) << 4)));
    __builtin_nontemporal_store(t, reinterpret_cast<f32x4*>(
        out_o + (size_t)(browbase + rowp)*DIM + wave*64 + cc*4));
  }

  // W: acc[mt][gr][i] = W[row=gr*16+c][m=128w+mt*16+4g+i]. Two 32-row halves
  // through priv (32 rows x 512B), NT-store 512B/row segments.
  #pragma unroll
  for (int h = 0; h < 2; ++h) {
    #pragma unroll
    for (int mt = 0; mt < 8; ++mt)
      #pragma unroll
      for (int grl = 0; grl < 2; ++grl) {
        int row = grl*16 + c;              // row within half
        *reinterpret_cast<f32x4*>(priv + row*512 + ((mt*64 + g*16) ^ (c << 4))) = acc[mt][2*h + grl];
      }
    #pragma unroll
    for (int p = 0; p < 16; ++p) {
      int rq = lane >> 5, cc = lane & 31;
      int rowp = 2*p + rq;
      f32x4 t = *reinterpret_cast<const f32x4*>(priv + rowp*512 + ((cc*16) ^ ((rowp & 15) << 4)));
      __builtin_nontemporal_store(t, reinterpret_cast<f32x4*>(
          out_w + (size_t)(browbase + h*32 + rowp)*MEMN + wave*128 + cc*4));
    }
  }
}

// Boundary scene diffs: i % 16 == 15 (one wave per i)
__global__ void scene_bound(const float* __restrict__ q, float* __restrict__ out_s, int B) {
  int widx = (blockIdx.x * blockDim.x + threadIdx.x) >> 6;
  int lane = threadIdx.x & 63;
  int i = widx * 16 + 15;
  if (i > B - 2) return;
  const float* a = q + (size_t)i * DIM + lane * 4;
  float4 x = *reinterpret_cast<const float4*>(a);
  float4 y = *reinterpret_cast<const float4*>(a + DIM);
  float dx = y.x-x.x, dy = y.y-x.y, dz = y.z-x.z, dw = y.w-x.w;
  float sd = dx*dx + dy*dy + dz*dz + dw*dw;
  #pragma unroll
  for (int o = 1; o < 64; o <<= 1) sd += __shfl_xor(sd, o);
  if (lane == 0) out_s[i] = (sqrtf(sd) < 0.8f) ? 1.0f : 0.0f;
}

extern "C" void kernel_launch(void* const* d_in, const int* in_sizes, int n_in,
                              void* d_out, int out_size, void* d_ws, size_t ws_size,
                              hipStream_t stream) {
  const float* q  = (const float*)d_in[0];
  const float* mk = (const float*)d_in[1];
  const float* mv = (const float*)d_in[2];
  int B = in_sizes[0] / DIM;            // 131072
  float* o = (float*)d_out;
  float* w = o + (size_t)B * DIM;
  float* s = w + (size_t)B * MEMN;
  u16* knf = (u16*)d_ws;                         // 256 KB
  u16* vtf = (u16*)((char*)d_ws + 262144);       // 256 KB
  prep_keys<<<128, 256, 0, stream>>>(mk, knf);
  prep_vals<<<128, 256, 0, stream>>>(mv, vtf);
  fused_main<<<B / 64, 256, 0, stream>>>(q, knf, vtf, o, w, s);
  int nwaves = B / 16;
  scene_bound<<<(nwaves + 3) / 4, 256, 0, stream>>>(q, s, B);
}